// Round 2
// baseline (797.528 us; speedup 1.0000x reference)
//
#include <hip/hip_runtime.h>
#include <stdint.h>

#define AS1 __attribute__((address_space(1)))
#define AS3 __attribute__((address_space(3)))

typedef float f32x4 __attribute__((ext_vector_type(4)));
typedef short bf16x8 __attribute__((ext_vector_type(8)));
typedef unsigned short u16;
typedef unsigned int u32;
typedef unsigned short u16x8 __attribute__((ext_vector_type(8)));

__device__ __forceinline__ u16 f2bf(float f) {
  union { float f; u32 u; } v; v.f = f;
  u32 r = v.u + 0x7fffu + ((v.u >> 16) & 1u);   // RNE
  return (u16)(r >> 16);
}
__device__ __forceinline__ float bf2f(u16 b) {
  union { float f; u32 u; } v; v.u = ((u32)b) << 16;
  return v.f;
}

// ---------------- kernel 1: pack weights (4x [512][512] fp32 -> bf16 [2048][512]) + biases
__global__ void pack_w(const float* __restrict__ wq, const float* __restrict__ wk,
                       const float* __restrict__ wv, const float* __restrict__ w1,
                       const float* __restrict__ bq, const float* __restrict__ bk,
                       const float* __restrict__ bv, const float* __restrict__ b1,
                       u16* __restrict__ WP, float* __restrict__ BIAS) {
  int idx = blockIdx.x * 256 + threadIdx.x;     // exactly 2048*512 threads
  int g = idx >> 9, k = idx & 511;
  const float* src = (g < 512) ? wq : (g < 1024) ? wk : (g < 1536) ? wv : w1;
  WP[idx] = f2bf(src[(g & 511) * 512 + k]);
  if (idx < 2048) {
    const float* bsrc = (idx < 512) ? bq : (idx < 1024) ? bk : (idx < 1536) ? bv : b1;
    BIAS[idx] = bsrc[idx & 511];
  }
}

// ---------------- kernel 2: X fp32 -> bf16
__global__ void cvt_x(const float* __restrict__ X, u16* __restrict__ XB) {
  size_t i = ((size_t)blockIdx.x * 256 + threadIdx.x) * 8;
  f32x4 a = *(const f32x4*)(X + i);
  f32x4 b = *(const f32x4*)(X + i + 4);
  u16x8 o;
  o[0] = f2bf(a[0]); o[1] = f2bf(a[1]); o[2] = f2bf(a[2]); o[3] = f2bf(a[3]);
  o[4] = f2bf(b[0]); o[5] = f2bf(b[1]); o[6] = f2bf(b[2]); o[7] = f2bf(b[3]);
  *(u16x8*)(XB + i) = o;
}

// ---------------- kernel 3: fused GEMM  C[65536][2048] = X[65536][512] * WP[2048][512]^T
// 128x128 tile, BK=32, 4 waves (2x2), 16x16x32 bf16 MFMA, global_load_lds width 16.
// by in [0,12): write Q/K/V bf16.  by in [12,16): h-projection -> relu -> dot w2 -> OBVP partials.
__global__ __launch_bounds__(256) void gemm_qkvh(
    const u16* __restrict__ XB, const u16* __restrict__ WP, const float* __restrict__ BIAS,
    const float* __restrict__ w2,
    u16* __restrict__ QBuf, u16* __restrict__ KBuf, u16* __restrict__ VBuf,
    float* __restrict__ OBVP) {
  __shared__ __align__(16) u16 As[128 * 32];
  __shared__ __align__(16) u16 Bs[128 * 32];
  int tid = threadIdx.x, lane = tid & 63, w = tid >> 6;
  int by = blockIdx.y;
  int mbase = blockIdx.x * 128, nbase = by * 128;
  int wr = w >> 1, wc = w & 1;
  const f32x4 zero = {0.f, 0.f, 0.f, 0.f};
  f32x4 acc[4][4];
#pragma unroll
  for (int i = 0; i < 4; ++i)
#pragma unroll
    for (int j = 0; j < 4; ++j) acc[i][j] = zero;

  for (int k0 = 0; k0 < 512; k0 += 32) {
#pragma unroll
    for (int it = 0; it < 2; ++it) {
      int f = it * 4096 + tid * 16;        // byte offset in 8 KiB tile
      int row = f >> 6, cb = f & 63;       // 64 B per row (32 bf16)
      const u16* srcA = XB + (size_t)(mbase + row) * 512 + k0 + (cb >> 1);
      const u16* srcB = WP + (size_t)(nbase + row) * 512 + k0 + (cb >> 1);
      __builtin_amdgcn_global_load_lds((const AS1 u32*)srcA, (AS3 u32*)((char*)As + f), 16, 0, 0);
      __builtin_amdgcn_global_load_lds((const AS1 u32*)srcB, (AS3 u32*)((char*)Bs + f), 16, 0, 0);
    }
    __syncthreads();
    int kb = (lane >> 4) * 16;             // k-byte within row for this lane group
    bf16x8 av[4], bv[4];
#pragma unroll
    for (int i = 0; i < 4; ++i)
      av[i] = *(const bf16x8*)((const char*)As + (wr * 64 + i * 16 + (lane & 15)) * 64 + kb);
#pragma unroll
    for (int i = 0; i < 4; ++i)
      bv[i] = *(const bf16x8*)((const char*)Bs + (wc * 64 + i * 16 + (lane & 15)) * 64 + kb);
#pragma unroll
    for (int i = 0; i < 4; ++i)
#pragma unroll
      for (int j = 0; j < 4; ++j)
        acc[i][j] = __builtin_amdgcn_mfma_f32_16x16x32_bf16(av[i], bv[j], acc[i][j], 0, 0, 0);
    __syncthreads();
  }

  if (by < 12) {
    // epilogue: bias, split into Q/K/V bf16 buffers
    u16* outb = (by < 4) ? QBuf : (by < 8) ? KBuf : VBuf;
#pragma unroll
    for (int j = 0; j < 4; ++j) {
      int gg = nbase + wc * 64 + j * 16 + (lane & 15);
      float bias = BIAS[gg];
      int col = gg & 511;
#pragma unroll
      for (int i = 0; i < 4; ++i) {
        int mrow = mbase + wr * 64 + i * 16 + (lane >> 4) * 4;
#pragma unroll
        for (int rg = 0; rg < 4; ++rg)
          outb[(size_t)(mrow + rg) * 512 + col] = f2bf(acc[i][j][rg] + bias);
      }
    }
  } else {
    // epilogue: h = relu(acc+bias); partial = sum over this wave's 64 cols of h*w2[col]
    float biasj[4], w2j[4];
#pragma unroll
    for (int j = 0; j < 4; ++j) {
      int gg = nbase + wc * 64 + j * 16 + (lane & 15);
      biasj[j] = BIAS[gg];
      w2j[j] = w2[gg - 1536];
    }
    int slice = (by - 12) * 2 + wc;
#pragma unroll
    for (int i = 0; i < 4; ++i) {
#pragma unroll
      for (int rg = 0; rg < 4; ++rg) {
        float p = 0.f;
#pragma unroll
        for (int j = 0; j < 4; ++j)
          p += fmaxf(acc[i][j][rg] + biasj[j], 0.0f) * w2j[j];
        p += __shfl_xor(p, 1);
        p += __shfl_xor(p, 2);
        p += __shfl_xor(p, 4);
        p += __shfl_xor(p, 8);
        if ((lane & 15) == 0) {
          int mrow = mbase + wr * 64 + i * 16 + (lane >> 4) * 4 + rg;
          OBVP[(size_t)slice * 65536 + mrow] = p;
        }
      }
    }
  }
}

// ---------------- kernel 4: OBV = sigmoid(sum of 8 partials + b2)
__global__ void sigmoid_obv(const float* __restrict__ OBVP, const float* __restrict__ b2,
                            float* __restrict__ OBV) {
  int m = blockIdx.x * 256 + threadIdx.x;
  float s = b2[0];
#pragma unroll
  for (int k = 0; k < 8; ++k) s += OBVP[(size_t)k * 65536 + m];
  OBV[m] = 1.0f / (1.0f + __expf(-s));
}

// ---------------- kernels 5/6: per-(b,r) transpose of V slice [128 t][512 h] -> VT[br][512 h][128 t]
// XOR-swizzled 32 KiB LDS tile; coalesced 16B on both global sides.
__global__ void transpose_v(const u16* __restrict__ V, u16* __restrict__ VT, int ver) {
  __shared__ __align__(16) u16 T[128 * 128];
  char* Tb = (char*)T;
  int tid = threadIdx.x;
  int br = blockIdx.x >> 2, hc = blockIdx.x & 3;
  int b = br >> 7, r = br & 127;
  int base0 = ver ? (b * 16384 + r) : (br * 128);
  int rstride = ver ? 128 : 1;
  int h0 = hc * 128;
#pragma unroll
  for (int it = 0; it < 8; ++it) {
    int f = it * 4096 + tid * 16;
    int t = f >> 8, cb = f & 255;          // 256 B per t-row (128 h bf16)
    u16x8 v = *(const u16x8*)(V + (size_t)(base0 + t * rstride) * 512 + h0 + (cb >> 1));
    int key = ((t >> 3) & 7) << 4;
    *(u16x8*)(Tb + t * 256 + (cb ^ key)) = v;
  }
  __syncthreads();
  size_t outbase = (size_t)br * 65536 + (size_t)h0 * 128;
#pragma unroll
  for (int it = 0; it < 8; ++it) {
    int F = it * 4096 + tid * 16;
    int hl = F >> 8, t0 = (F & 255) >> 1;
    u16x8 o;
#pragma unroll
    for (int e = 0; e < 8; ++e) {
      int t = t0 + e;
      int key = ((t >> 3) & 7) << 4;
      o[e] = *(const u16*)(Tb + t * 256 + ((2 * hl) ^ key));
    }
    *(u16x8*)(VT + outbase + (size_t)hl * 128 + t0) = o;
  }
}

// ---------------- kernels 7/8: axis attention. One block per (b, r). 4 waves.
// S = Q K^T (MFMA), gate by obv[key], mask, wave-parallel softmax, P->LDS bf16, PV via staged V^T.
__global__ __launch_bounds__(256) void attn_k(
    const u16* __restrict__ QB, const u16* __restrict__ KB, const u16* __restrict__ VT,
    const float* __restrict__ OBV, const int* __restrict__ MASK,
    float* __restrict__ OUT, int ver) {
  __shared__ __align__(16) char L[52224];  // PhaseA: Qs[0..10240)|Ks[10240..20480)  PhaseB: Ps[0..34816)|Vts[34816..52224)
  int tid = threadIdx.x, lane = tid & 63, w = tid >> 6;
  int br = blockIdx.x, b = br >> 7, r = br & 127;
  int base = ver ? (b * 16384 + r) : (br * 128);
  int stride = ver ? 128 : 1;

  float obvc[8];
  u32 maskbits = 0;
#pragma unroll
  for (int j = 0; j < 8; ++j) {
    int t = j * 16 + (lane & 15);
    int idx = base + t * stride;
    obvc[j] = OBV[idx];
    if (MASK[idx] != 0) maskbits |= (1u << j);
  }

  char* Qs = L;
  char* Ks = L + 10240;
  const f32x4 zero = {0.f, 0.f, 0.f, 0.f};
  f32x4 acc[2][8];
#pragma unroll
  for (int i = 0; i < 2; ++i)
#pragma unroll
    for (int j = 0; j < 8; ++j) acc[i][j] = zero;

  // Phase A: S = Q K^T over K=512, BK=32, padded LDS rows (stride 80 B, conflict-free)
  for (int k0 = 0; k0 < 512; k0 += 32) {
#pragma unroll
    for (int it = 0; it < 2; ++it) {
      int f = it * 4096 + tid * 16;
      int row = f >> 6, cb = f & 63;
      size_t g = (size_t)(base + row * stride) * 512 + k0 + (cb >> 1);
      u16x8 vq = *(const u16x8*)(QB + g);
      u16x8 vk = *(const u16x8*)(KB + g);
      *(u16x8*)(Qs + row * 80 + cb) = vq;
      *(u16x8*)(Ks + row * 80 + cb) = vk;
    }
    __syncthreads();
    int kb = (lane >> 4) * 16;
    bf16x8 aq[2], bk[8];
#pragma unroll
    for (int i = 0; i < 2; ++i)
      aq[i] = *(const bf16x8*)(Qs + (w * 32 + i * 16 + (lane & 15)) * 80 + kb);
#pragma unroll
    for (int j = 0; j < 8; ++j)
      bk[j] = *(const bf16x8*)(Ks + (j * 16 + (lane & 15)) * 80 + kb);
#pragma unroll
    for (int i = 0; i < 2; ++i)
#pragma unroll
      for (int j = 0; j < 8; ++j)
        acc[i][j] = __builtin_amdgcn_mfma_f32_16x16x32_bf16(aq[i], bk[j], acc[i][j], 0, 0, 0);
    __syncthreads();
  }

  // softmax in-register: rows = (lane>>4)*4+rg (+16i+32w), cols across (lane&15) x 8 frags
  const float scale = 0.04419417382415922f;  // 1/sqrt(512)
#pragma unroll
  for (int i = 0; i < 2; ++i) {
#pragma unroll
    for (int rg = 0; rg < 4; ++rg) {
      float mx = -3.0e38f;
#pragma unroll
      for (int j = 0; j < 8; ++j) {
        float s = ((maskbits >> j) & 1u) ? acc[i][j][rg] * scale * obvc[j] : -1.0e9f;
        acc[i][j][rg] = s;
        mx = fmaxf(mx, s);
      }
      mx = fmaxf(mx, __shfl_xor(mx, 1));
      mx = fmaxf(mx, __shfl_xor(mx, 2));
      mx = fmaxf(mx, __shfl_xor(mx, 4));
      mx = fmaxf(mx, __shfl_xor(mx, 8));
      float sum = 0.f;
#pragma unroll
      for (int j = 0; j < 8; ++j) {
        float e = __expf(acc[i][j][rg] - mx);
        acc[i][j][rg] = e;
        sum += e;
      }
      sum += __shfl_xor(sum, 1);
      sum += __shfl_xor(sum, 2);
      sum += __shfl_xor(sum, 4);
      sum += __shfl_xor(sum, 8);
      float inv = 1.0f / sum;
#pragma unroll
      for (int j = 0; j < 8; ++j) acc[i][j][rg] *= inv;
    }
  }

  // write P (bf16) to LDS, rows stride 272 B (conflict-free b128 reads)
  char* Ps = L;
#pragma unroll
  for (int i = 0; i < 2; ++i)
#pragma unroll
    for (int j = 0; j < 8; ++j)
#pragma unroll
      for (int rg = 0; rg < 4; ++rg) {
        int row = w * 32 + i * 16 + (lane >> 4) * 4 + rg;
        int col = j * 16 + (lane & 15);
        *(u16*)(Ps + row * 272 + col * 2) = f2bf(acc[i][j][rg]);
      }
  __syncthreads();

  // Phase B: out = P V, V^T staged 64 h-rows at a time
  char* Vts = L + 34816;
  size_t vtbase = (size_t)br * 65536;
  for (int hp = 0; hp < 8; ++hp) {
#pragma unroll
    for (int it = 0; it < 4; ++it) {
      int f = it * 4096 + tid * 16;
      int row = f >> 8, cb = f & 255;
      u16x8 v = *(const u16x8*)(VT + vtbase + hp * 8192 + (f >> 1));
      *(u16x8*)(Vts + row * 272 + cb) = v;
    }
    __syncthreads();
    f32x4 oacc[2][4];
#pragma unroll
    for (int i = 0; i < 2; ++i)
#pragma unroll
      for (int j = 0; j < 4; ++j) oacc[i][j] = zero;
#pragma unroll
    for (int ks = 0; ks < 4; ++ks) {
      int kb2 = ks * 64 + (lane >> 4) * 16;
      bf16x8 ap[2], bv[4];
#pragma unroll
      for (int i = 0; i < 2; ++i)
        ap[i] = *(const bf16x8*)(Ps + (w * 32 + i * 16 + (lane & 15)) * 272 + kb2);
#pragma unroll
      for (int j = 0; j < 4; ++j)
        bv[j] = *(const bf16x8*)(Vts + (j * 16 + (lane & 15)) * 272 + kb2);
#pragma unroll
      for (int i = 0; i < 2; ++i)
#pragma unroll
        for (int j = 0; j < 4; ++j)
          oacc[i][j] = __builtin_amdgcn_mfma_f32_16x16x32_bf16(ap[i], bv[j], oacc[i][j], 0, 0, 0);
    }
#pragma unroll
    for (int i = 0; i < 2; ++i)
#pragma unroll
      for (int j = 0; j < 4; ++j) {
        int h = hp * 64 + j * 16 + (lane & 15);
#pragma unroll
        for (int rg = 0; rg < 4; ++rg) {
          int jr = w * 32 + i * 16 + (lane >> 4) * 4 + rg;
          size_t m = (size_t)(base + jr * stride);
          float vv = oacc[i][j][rg];
          if (ver) OUT[m * 512 + h] += vv;
          else     OUT[m * 512 + h] = vv;
        }
      }
    __syncthreads();
  }
}

extern "C" void kernel_launch(void* const* d_in, const int* in_sizes, int n_in,
                              void* d_out, int out_size, void* d_ws, size_t ws_size,
                              hipStream_t stream) {
  const float* X    = (const float*)d_in[0];
  const int*   MASK = (const int*)d_in[1];
  const float* wq_w = (const float*)d_in[2];
  const float* wq_b = (const float*)d_in[3];
  const float* wk_w = (const float*)d_in[4];
  const float* wk_b = (const float*)d_in[5];
  const float* wv_w = (const float*)d_in[6];
  const float* wv_b = (const float*)d_in[7];
  const float* w1   = (const float*)d_in[8];
  const float* b1   = (const float*)d_in[9];
  const float* w2   = (const float*)d_in[10];
  const float* b2   = (const float*)d_in[11];
  float* OUT = (float*)d_out;
  char* ws = (char*)d_ws;
  const size_t MB = 1ull << 20;

  u16*  XB   = (u16*)(ws + 0 * MB);      // 64 MiB; reused as VT_ver after GEMM
  u16*  QBuf = (u16*)(ws + 64 * MB);     // 64 MiB
  u16*  KBuf = (u16*)(ws + 128 * MB);    // 64 MiB
  u16*  VBuf = (u16*)(ws + 192 * MB);    // 64 MiB
  u16*  VTH  = (u16*)(ws + 256 * MB);    // 64 MiB
  u16*  WP   = (u16*)(ws + 320 * MB);    // 2 MiB
  float* BIAS = (float*)(ws + 322 * MB); // 8 KiB
  float* OBV  = (float*)(ws + 322 * MB + (256ull << 10)); // 256 KiB
  float* OBVP = (float*)(ws + 323 * MB); // 2 MiB
  u16*  VTV = XB;

  pack_w<<<dim3(4096), dim3(256), 0, stream>>>(wq_w, wk_w, wv_w, w1, wq_b, wk_b, wv_b, b1, WP, BIAS);
  cvt_x<<<dim3(16384), dim3(256), 0, stream>>>(X, XB);
  gemm_qkvh<<<dim3(512, 16), dim3(256), 0, stream>>>(XB, WP, BIAS, w2, QBuf, KBuf, VBuf, OBVP);
  sigmoid_obv<<<dim3(256), dim3(256), 0, stream>>>(OBVP, b2, OBV);
  transpose_v<<<dim3(2048), dim3(256), 0, stream>>>(VBuf, VTH, 0);
  transpose_v<<<dim3(2048), dim3(256), 0, stream>>>(VBuf, VTV, 1);
  attn_k<<<dim3(512), dim3(256), 0, stream>>>(QBuf, KBuf, VTH, OBV, MASK, OUT, 0);
  attn_k<<<dim3(512), dim3(256), 0, stream>>>(QBuf, KBuf, VTV, OBV, MASK, OUT, 1);
}